// Round 7
// baseline (453.736 us; speedup 1.0000x reference)
//
#include <hip/hip_runtime.h>
#include <math.h>

typedef unsigned short u16;
typedef __attribute__((ext_vector_type(8))) short bf16x8;
typedef __attribute__((ext_vector_type(4))) float f32x4;

#define NSENS 9
#define NEDGE 72
#define NPAIR 36
#define HDIM 128
#define NLAYER 4
#define FEPS 1e-8f

#define ST    136   // bf16 row stride (272B)
#define STNIN 264   // [h_n | agg] row stride
#define STPH  40    // phys row stride, K padded 6->32

__device__ __forceinline__ u16 f2bf(float f) {           // RNE fp32->bf16
    unsigned u = __float_as_uint(f);
    return (u16)((u + 0x7FFFu + ((u >> 16) & 1u)) >> 16);
}
__device__ __forceinline__ float bf2f(u16 h) { return __uint_as_float(((unsigned)h) << 16); }

__device__ __forceinline__ unsigned cvt2(float lo, float hi) {
#if defined(__has_builtin)
#if __has_builtin(__builtin_amdgcn_cvt_pk_bf16_f32)
    typedef __attribute__((ext_vector_type(2))) __bf16 bf16x2_t;
    bf16x2_t t = __builtin_amdgcn_cvt_pk_bf16_f32(lo, hi);
    unsigned u; __builtin_memcpy(&u, &t, 4); return u;
#else
    return ((unsigned)f2bf(hi) << 16) | (unsigned)f2bf(lo);
#endif
#else
    return ((unsigned)f2bf(hi) << 16) | (unsigned)f2bf(lo);
#endif
}

// ---- packed-weight layout offsets in d_ws (u16 units) ----
// B-fragment order: block(kb,nt) = 512 u16, element ((kb*NT+nt)*64 + lane)*8 + j,
// holding W[kb*32 + (lane>>4)*8 + j][nt*16 + (lane&15)]  (zero-padded past Ksrc).
#define SZ_EE1 (1*8*512)
#define SZ_EE2 (4*8*512)
#define SZ_EW1 (12*8*512)
#define SZ_EW2 (4*8*512)
#define SZ_NW1 (8*8*512)
#define SZ_NW2 (4*8*512)
#define SZ_DW1 (4*4*512)
#define OFF_EE1 0
#define OFF_EE2 (OFF_EE1 + SZ_EE1)
#define OFF_EW1 (OFF_EE2 + SZ_EE2)
#define OFF_EW2 (OFF_EW1 + 4*SZ_EW1)
#define OFF_NW1 (OFF_EW2 + 4*SZ_EW2)
#define OFF_NW2 (OFF_NW1 + 4*SZ_NW1)
#define OFF_DW1 (OFF_NW2 + 4*SZ_NW2)

__device__ __forceinline__ void pack_one(const float* __restrict__ s, u16* __restrict__ d,
                                         int Ksrc, int N, int NT, int kbnt) {
    const int kb = kbnt / NT, nt = kbnt % NT;
    const int ln = threadIdx.x, q = ln >> 4, c = ln & 15;
    const int n  = nt * 16 + c;
    u16* dp = d + ((kb * NT + nt) * 64 + ln) * 8;
#pragma unroll
    for (int j = 0; j < 8; ++j) {
        int k = kb * 32 + q * 8 + j;
        dp[j] = f2bf((k < Ksrc) ? s[k * N + n] : 0.f);
    }
}

__global__ void pack_all(const float* __restrict__ ee1, const float* __restrict__ ee2,
                         const float* __restrict__ ew1, const float* __restrict__ ew2,
                         const float* __restrict__ nw1, const float* __restrict__ nw2,
                         const float* __restrict__ dw1, u16* __restrict__ ws) {
    int b = blockIdx.x;
    if (b < 8)        { pack_one(ee1, ws + OFF_EE1, 6, 128, 8, b); return; }
    b -= 8;
    if (b < 32)       { pack_one(ee2, ws + OFF_EE2, 128, 128, 8, b); return; }
    b -= 32;
    if (b < 384)      { int l = b / 96;
                        pack_one(ew1 + l*384*128, ws + OFF_EW1 + l*SZ_EW1, 384, 128, 8, b % 96); return; }
    b -= 384;
    if (b < 128)      { int l = b / 32;
                        pack_one(ew2 + l*128*128, ws + OFF_EW2 + l*SZ_EW2, 128, 128, 8, b % 32); return; }
    b -= 128;
    if (b < 256)      { int l = b / 64;
                        pack_one(nw1 + l*256*128, ws + OFF_NW1 + l*SZ_NW1, 256, 128, 8, b % 64); return; }
    b -= 256;
    if (b < 128)      { int l = b / 32;
                        pack_one(nw2 + l*128*128, ws + OFF_NW2 + l*SZ_NW2, 128, 128, 8, b % 32); return; }
    b -= 128;
    pack_one(dw1, ws + OFF_DW1, 128, 64, 4, b);
}

// Wave-level GEMM: bc0 = pre-loaded first B-fragment (issued BEFORE the phase
// barrier so its L2 latency overlaps the barrier drain); register double-buffer
// for subsequent kb.
template<int NMT, int NKB, int NT, typename FA>
__device__ __forceinline__ void wave_gemm(const u16* __restrict__ Wp, int nt, int ln,
                                          bf16x8 bc, FA fa, f32x4* acc) {
    const u16* wp = Wp + (nt * 64 + ln) * 8;
#pragma unroll
    for (int kb = 0; kb < NKB; ++kb) {
        bf16x8 bn;
        if (kb + 1 < NKB) bn = *(const bf16x8*)(wp + (kb + 1) * NT * 512);
#pragma unroll
        for (int mt = 0; mt < NMT; ++mt) {
            bf16x8 a = fa(mt, kb);
            acc[mt] = __builtin_amdgcn_mfma_f32_16x16x32_bf16(a, bc, acc[mt], 0, 0, 0);
        }
        if (kb + 1 < NKB) bc = bn;
    }
}

#define BACC(A, N, b) do { _Pragma("unroll") for (int _i = 0; _i < (N); ++_i) \
                           (A)[_i] = (f32x4){(b), (b), (b), (b)}; } while (0)

// One block (512 thr = 8 waves) per graph; 2-phase layers (EW1+NW1 | EW2+NW2),
// cross-barrier B prefetch. bf16 mirrors ~54 KB LDS -> 2 blocks/CU; fp32 residual
// masters in registers. MFMA C/D: col=lane&15, row=(lane>>4)*4+reg.
extern "C" __global__ void __launch_bounds__(512, 2)
gnn_mfma(const float* __restrict__ x_nodes, const float* __restrict__ damage_locs,
         const float* __restrict__ enc_n_w, const float* __restrict__ enc_n_b,
         const float* __restrict__ enc_e_b1, const float* __restrict__ enc_e_b2,
         const float* __restrict__ edge_b1, const float* __restrict__ edge_b2,
         const float* __restrict__ node_b1, const float* __restrict__ node_b2,
         const float* __restrict__ dec_b1, const float* __restrict__ dec_w2,
         const float* __restrict__ dec_b2,
         const u16* __restrict__ wpack, float* __restrict__ out)
{
    __shared__ __align__(16) u16 smem[169 * ST + 16 * STNIN];
    __shared__ float s_x[NSENS * 2];
    __shared__ float s_dmg[2];
    __shared__ float s_val[NEDGE];
    __shared__ int s_src[NEDGE], s_dst[NEDGE];

    u16* b_he  = smem;               // 72 x ST   edge features (bf16 mirror)
    u16* b_t   = smem + 72 * ST;     // 72 x ST   MLP hidden (edge) / decoder hidden
    u16* b_hn  = smem + 144 * ST;    // 9 x ST    node features
    u16* b_nt  = smem + 153 * ST;    // 16 x ST   node hidden
    u16* b_nin = smem + 169 * ST;    // 16 x STNIN  [h_n | agg]
    u16* b_ph  = b_he;               // alias: phys dead once EE1 consumed it

    const int g   = blockIdx.x;
    const int tid = threadIdx.x;
    const int wv  = tid >> 6, ln = tid & 63;
    const int q   = ln >> 4,  cl = ln & 15;
    const int col = wv * 16 + cl;          // this wave's output column (128-wide GEMMs)

    // 4-row column store (C-fragment -> bf16 mirror)
    auto st4 = [&](u16* buf, int stride, int c, int Rb, int Rlim,
                   float v0, float v1, float v2, float v3) {
        unsigned d01 = cvt2(v0, v1), d23 = cvt2(v2, v3);
        if (Rb + 0 < Rlim) buf[(Rb + 0) * stride + c] = (u16)d01;
        if (Rb + 1 < Rlim) buf[(Rb + 1) * stride + c] = (u16)(d01 >> 16);
        if (Rb + 2 < Rlim) buf[(Rb + 2) * stride + c] = (u16)d23;
        if (Rb + 3 < Rlim) buf[(Rb + 3) * stride + c] = (u16)(d23 >> 16);
    };
    auto preB = [&](const u16* Wp, int nt) -> bf16x8 {
        return *(const bf16x8*)(Wp + (nt * 64 + ln) * 8);
    };

    // ---- zero phys pad region + b_nin rows 9..15 (never written, must be finite) ----
    {
        uint4 z = {0, 0, 0, 0};
        uint4* zp = (uint4*)b_ph;                       // 72*STPH = 2880 u16 = 360 uint4
        for (int i = tid; i < 360; i += 512) zp[i] = z;
        unsigned* znp = (unsigned*)(b_nin + 9 * STNIN); // 7*264 = 1848 u16 = 924 dw
        for (int i = tid; i < 924; i += 512) znp[i] = 0;
    }
    if (tid < NSENS * 2) s_x[tid] = x_nodes[g * NSENS * 2 + tid];
    if (tid < 2)         s_dmg[tid] = damage_locs[g * 2 + tid];
    if (tid < NEDGE) {
        int p = tid >> 1;
        int i = 0, rem = p, cnt = 8;
        while (rem >= cnt) { rem -= cnt; --cnt; ++i; }
        int j = i + 1 + rem;
        s_src[tid] = (tid & 1) ? j : i;
        s_dst[tid] = (tid & 1) ? i : j;
    }
    __syncthreads();

    // ---- phys features -> b_ph (rows<72, cols 0..5 of 32) ----
    if (tid < NEDGE) {
        const int si = s_src[tid], di = s_dst[tid];
        const float sx = s_x[2*si], sy = s_x[2*si+1];
        const float dx = s_x[2*di], dy = s_x[2*di+1];
        const float gx = s_dmg[0],  gy = s_dmg[1];
        const float vx = sx - dx, vy = sy - dy;
        const float vv = vx*vx + vy*vy;
        const float elen = sqrtf(vv + FEPS);
        const float l2 = fmaxf(vv, FEPS);
        float t = ((gx - sx) * (dx - sx) + (gy - sy) * (dy - sy)) / l2;
        t = fminf(fmaxf(t, 0.f), 1.f);
        const float px = sx + t * (dx - sx), py = sy + t * (dy - sy);
        u16* ph = b_ph + tid * STPH;
        ph[0] = f2bf(vx); ph[1] = f2bf(vy); ph[2] = f2bf(elen);
        ph[3] = f2bf(sqrtf((gx-px)*(gx-px) + (gy-py)*(gy-py) + FEPS));
        ph[4] = f2bf(sqrtf((sx-gx)*(sx-gx) + (sy-gy)*(sy-gy) + FEPS));
        ph[5] = f2bf(sqrtf((dx-gx)*(dx-gx) + (dy-gy)*(dy-gy) + FEPS));
    }

    // ---- node encoder (K=2) -> fp32 master m_hn + bf16 mirror (9-row buffer) ----
    f32x4 m_hn;
    {
        const float w0 = enc_n_w[col], w1 = enc_n_w[HDIM + col], bb = enc_n_b[col];
#pragma unroll
        for (int r = 0; r < 4; ++r) {
            const int R = q * 4 + r;
            m_hn[r] = (R < NSENS) ? fmaf(s_x[2*R], w0, fmaf(s_x[2*R+1], w1, bb)) : 0.f;
        }
        st4(b_hn, ST, col, q * 4, NSENS, m_hn[0], m_hn[1], m_hn[2], m_hn[3]);
    }

    // per-lane row offsets (clamped to row 71 -> garbage lands in discarded C rows)
    int rowS[5], rowD[5], rowT[5], rowP[5];
#pragma unroll
    for (int mt = 0; mt < 5; ++mt) {
        int e = mt * 16 + cl; if (e >= NEDGE) e = NEDGE - 1;
        rowS[mt] = s_src[e] * ST; rowD[mt] = s_dst[e] * ST;
        rowT[mt] = e * ST;        rowP[mt] = e * STPH;
    }

    auto fa_t   = [&](int mt, int kb) -> bf16x8 {
        return *(const bf16x8*)(b_t + rowT[mt] + cl * 0 + kb * 32 + q * 8); };
    auto fa_ph  = [&](int mt, int kb) -> bf16x8 {
        return *(const bf16x8*)(b_ph + rowP[mt] + q * 8); };
    auto fa_nin = [&](int mt, int kb) -> bf16x8 {
        return *(const bf16x8*)(b_nin + cl * STNIN + kb * 32 + q * 8); };
    auto fa_nt  = [&](int mt, int kb) -> bf16x8 {
        return *(const bf16x8*)(b_nt + cl * ST + kb * 32 + q * 8); };
    auto fa_ein = [&](int mt, int kb) -> bf16x8 {
        const u16* p;
        if (kb < 4)      p = b_hn + rowS[mt] + kb * 32;
        else if (kb < 8) p = b_hn + rowD[mt] + (kb - 4) * 32;
        else             p = b_he + rowT[mt] + (kb - 8) * 32;
        return *(const bf16x8*)(p + q * 8); };

    // write [h_n | (sum-h)/8] for the next layer's node MLP1
    auto write_nin = [&]() {
        float p4 = m_hn[0] + m_hn[1] + m_hn[2] + m_hn[3]; // pad rows are 0 in regs
        p4 += __shfl_xor(p4, 16);
        p4 += __shfl_xor(p4, 32);
        st4(b_nin, STNIN, col, q * 4, NSENS, m_hn[0], m_hn[1], m_hn[2], m_hn[3]);
        st4(b_nin, STNIN, HDIM + col, q * 4, NSENS,
            (p4 - m_hn[0]) * 0.125f, (p4 - m_hn[1]) * 0.125f,
            (p4 - m_hn[2]) * 0.125f, (p4 - m_hn[3]) * 0.125f);
    };

    f32x4 m_he[5];
    bf16x8 pE = preB(wpack + OFF_EE1, wv);   // prefetch EE1's first B before barrier
    __syncthreads();

    // ---- edge encoder GEMM1: relu(phys @ W1 + b1) -> b_t ----
    {
        f32x4 acc[5]; BACC(acc, 5, enc_e_b1[col]);
        wave_gemm<5, 1, 8>(wpack + OFF_EE1, wv, ln, pE, fa_ph, acc);
#pragma unroll
        for (int mt = 0; mt < 5; ++mt)
            st4(b_t, ST, col, mt * 16 + q * 4, NEDGE,
                fmaxf(acc[mt][0], 0.f), fmaxf(acc[mt][1], 0.f),
                fmaxf(acc[mt][2], 0.f), fmaxf(acc[mt][3], 0.f));
        pE = preB(wpack + OFF_EE2, wv);
    }
    __syncthreads();
    // ---- edge encoder GEMM2 -> m_he init + b_he mirror; initial b_nin ----
    bf16x8 pN;
    {
        f32x4 acc[5]; BACC(acc, 5, enc_e_b2[col]);
        wave_gemm<5, 4, 8>(wpack + OFF_EE2, wv, ln, pE, fa_t, acc);
#pragma unroll
        for (int mt = 0; mt < 5; ++mt) {
            m_he[mt] = acc[mt];
            st4(b_he, ST, col, mt * 16 + q * 4, NEDGE,
                m_he[mt][0], m_he[mt][1], m_he[mt][2], m_he[mt][3]);
        }
        write_nin();
        pE = preB(wpack + OFF_EW1, wv);
        pN = preB(wpack + OFF_NW1, wv);
    }
    __syncthreads();

    // ---- message-passing layers: 2 phases each ----
    for (int l = 0; l < NLAYER; ++l) {
        // phase A: edge MLP1 + node MLP1 (both read last layer's mirrors)
        {
            f32x4 accE[5]; BACC(accE, 5, edge_b1[l * HDIM + col]);
            wave_gemm<5, 12, 8>(wpack + OFF_EW1 + l * SZ_EW1, wv, ln, pE, fa_ein, accE);
            f32x4 accN[1]; BACC(accN, 1, node_b1[l * HDIM + col]);
            wave_gemm<1, 8, 8>(wpack + OFF_NW1 + l * SZ_NW1, wv, ln, pN, fa_nin, accN);
#pragma unroll
            for (int mt = 0; mt < 5; ++mt)
                st4(b_t, ST, col, mt * 16 + q * 4, NEDGE,
                    fmaxf(accE[mt][0], 0.f), fmaxf(accE[mt][1], 0.f),
                    fmaxf(accE[mt][2], 0.f), fmaxf(accE[mt][3], 0.f));
            st4(b_nt, ST, col, q * 4, 16,
                fmaxf(accN[0][0], 0.f), fmaxf(accN[0][1], 0.f),
                fmaxf(accN[0][2], 0.f), fmaxf(accN[0][3], 0.f));
            pE = preB(wpack + OFF_EW2 + l * SZ_EW2, wv);
            pN = preB(wpack + OFF_NW2 + l * SZ_NW2, wv);
        }
        __syncthreads();
        // phase B: edge MLP2 + node MLP2 -> masters += ; refresh mirrors + b_nin
        {
            f32x4 accE[5]; BACC(accE, 5, edge_b2[l * HDIM + col]);
            wave_gemm<5, 4, 8>(wpack + OFF_EW2 + l * SZ_EW2, wv, ln, pE, fa_t, accE);
            f32x4 accN[1]; BACC(accN, 1, node_b2[l * HDIM + col]);
            wave_gemm<1, 4, 8>(wpack + OFF_NW2 + l * SZ_NW2, wv, ln, pN, fa_nt, accN);
#pragma unroll
            for (int mt = 0; mt < 5; ++mt) {
#pragma unroll
                for (int r = 0; r < 4; ++r) m_he[mt][r] += accE[mt][r];
                st4(b_he, ST, col, mt * 16 + q * 4, NEDGE,
                    m_he[mt][0], m_he[mt][1], m_he[mt][2], m_he[mt][3]);
            }
#pragma unroll
            for (int r = 0; r < 4; ++r)
                if (q * 4 + r < NSENS) m_hn[r] += accN[0][r];
            st4(b_hn, ST, col, q * 4, NSENS, m_hn[0], m_hn[1], m_hn[2], m_hn[3]);
            write_nin();
            if (l + 1 < NLAYER) {
                pE = preB(wpack + OFF_EW1 + (l + 1) * SZ_EW1, wv);
                pN = preB(wpack + OFF_NW1 + (l + 1) * SZ_NW1, wv);
            } else {
                pE = preB(wpack + OFF_DW1, wv & 3);
            }
        }
        __syncthreads();
    }

    // ---- decoder GEMM1 (N=64): relu(h_e @ dec_w1 + b1) -> b_t cols 0..63 ----
    {
        const int ntd = wv & 3;
        const int mt0 = (wv < 4) ? 0 : 2;     // waves 0-3: mt 0-2; waves 4-7: mt 2-4
        int rowDd[3];
#pragma unroll
        for (int mt = 0; mt < 3; ++mt) {
            int e = (mt0 + mt) * 16 + cl; if (e >= NEDGE) e = NEDGE - 1;
            rowDd[mt] = e * ST;
        }
        auto fa_d = [&](int mt, int kb) -> bf16x8 {
            return *(const bf16x8*)(b_he + rowDd[mt] + kb * 32 + q * 8); };
        const int c64 = ntd * 16 + cl;
        f32x4 acc[3]; BACC(acc, 3, dec_b1[c64]);  // (mt=2 twice -> same-value race, benign)
        wave_gemm<3, 4, 4>(wpack + OFF_DW1, ntd, ln, pE, fa_d, acc);
#pragma unroll
        for (int mt = 0; mt < 3; ++mt)
            st4(b_t, ST, c64, (mt0 + mt) * 16 + q * 4, NEDGE,
                fmaxf(acc[mt][0], 0.f), fmaxf(acc[mt][1], 0.f),
                fmaxf(acc[mt][2], 0.f), fmaxf(acc[mt][3], 0.f));
    }
    __syncthreads();
    // ---- decoder GEMM2 (N=1) + sigmoid ----
    if (tid < NEDGE) {
        float a = dec_b2[0];
        const u16* tt = b_t + tid * ST;
#pragma unroll
        for (int k = 0; k < 64; ++k) a = fmaf(bf2f(tt[k]), dec_w2[k], a);
        s_val[tid] = 1.f / (1.f + expf(-a));
    }
    __syncthreads();
    if (tid < NPAIR)
        out[g * NPAIR + tid] = 0.5f * (s_val[2 * tid] + s_val[2 * tid + 1]);
}

extern "C" void kernel_launch(void* const* d_in, const int* in_sizes, int n_in,
                              void* d_out, int out_size, void* d_ws, size_t ws_size,
                              hipStream_t stream) {
    const float* x_nodes     = (const float*)d_in[0];
    const float* damage_locs = (const float*)d_in[1];
    const float* enc_n_w  = (const float*)d_in[2];
    const float* enc_n_b  = (const float*)d_in[3];
    const float* enc_e_w1 = (const float*)d_in[4];
    const float* enc_e_b1 = (const float*)d_in[5];
    const float* enc_e_w2 = (const float*)d_in[6];
    const float* enc_e_b2 = (const float*)d_in[7];
    const float* edge_w1  = (const float*)d_in[8];
    const float* edge_b1  = (const float*)d_in[9];
    const float* edge_w2  = (const float*)d_in[10];
    const float* edge_b2  = (const float*)d_in[11];
    const float* node_w1  = (const float*)d_in[12];
    const float* node_b1  = (const float*)d_in[13];
    const float* node_w2  = (const float*)d_in[14];
    const float* node_b2  = (const float*)d_in[15];
    const float* dec_w1   = (const float*)d_in[16];
    const float* dec_b1   = (const float*)d_in[17];
    const float* dec_w2   = (const float*)d_in[18];
    const float* dec_b2   = (const float*)d_in[19];
    float* out = (float*)d_out;
    u16* ws = (u16*)d_ws;

    hipLaunchKernelGGL(pack_all, dim3(952), dim3(64), 0, stream,
                       enc_e_w1, enc_e_w2, edge_w1, edge_w2, node_w1, node_w2, dec_w1, ws);

    const int ngraph = in_sizes[1] / 2;   // damage_locs is [B,2]
    hipLaunchKernelGGL(gnn_mfma, dim3(ngraph), dim3(512), 0, stream,
                       x_nodes, damage_locs, enc_n_w, enc_n_b,
                       enc_e_b1, enc_e_b2, edge_b1, edge_b2,
                       node_b1, node_b2, dec_b1, dec_w2, dec_b2,
                       ws, out);
}

// Round 8
// 365.267 us; speedup vs baseline: 1.2422x; 1.2422x over previous
//
#include <hip/hip_runtime.h>
#include <math.h>

typedef unsigned short u16;
typedef __attribute__((ext_vector_type(8))) short bf16x8;
typedef __attribute__((ext_vector_type(4))) float f32x4;

#define NSENS 9
#define NEDGE 72
#define NPAIR 36
#define HDIM 128
#define NLAYER 4
#define FEPS 1e-8f

#define ST    136   // bf16 row stride (272B)
#define STNIN 264   // [h_n | agg] row stride
#define STPH  40    // phys row stride, K padded 6->32

__device__ __forceinline__ u16 f2bf(float f) {           // RNE fp32->bf16
    unsigned u = __float_as_uint(f);
    return (u16)((u + 0x7FFFu + ((u >> 16) & 1u)) >> 16);
}
__device__ __forceinline__ float bf2f(u16 h) { return __uint_as_float(((unsigned)h) << 16); }

__device__ __forceinline__ unsigned cvt2(float lo, float hi) {
#if defined(__has_builtin)
#if __has_builtin(__builtin_amdgcn_cvt_pk_bf16_f32)
    typedef __attribute__((ext_vector_type(2))) __bf16 bf16x2_t;
    bf16x2_t t = __builtin_amdgcn_cvt_pk_bf16_f32(lo, hi);
    unsigned u; __builtin_memcpy(&u, &t, 4); return u;
#else
    return ((unsigned)f2bf(hi) << 16) | (unsigned)f2bf(lo);
#endif
#else
    return ((unsigned)f2bf(hi) << 16) | (unsigned)f2bf(lo);
#endif
}

// ---- packed-weight layout offsets in d_ws (u16 units) ----
// B-fragment order: block(kb,nt) = 512 u16, element ((kb*NT+nt)*64 + lane)*8 + j,
// holding W[kb*32 + (lane>>4)*8 + j][nt*16 + (lane&15)]  (zero-padded past Ksrc).
#define SZ_EE1 (1*8*512)
#define SZ_EE2 (4*8*512)
#define SZ_EW1 (12*8*512)
#define SZ_EW2 (4*8*512)
#define SZ_NW1 (8*8*512)
#define SZ_NW2 (4*8*512)
#define SZ_DW1 (4*4*512)
#define OFF_EE1 0
#define OFF_EE2 (OFF_EE1 + SZ_EE1)
#define OFF_EW1 (OFF_EE2 + SZ_EE2)
#define OFF_EW2 (OFF_EW1 + 4*SZ_EW1)
#define OFF_NW1 (OFF_EW2 + 4*SZ_EW2)
#define OFF_NW2 (OFF_NW1 + 4*SZ_NW1)
#define OFF_DW1 (OFF_NW2 + 4*SZ_NW2)

__device__ __forceinline__ void pack_one(const float* __restrict__ s, u16* __restrict__ d,
                                         int Ksrc, int N, int NT, int kbnt) {
    const int kb = kbnt / NT, nt = kbnt % NT;
    const int ln = threadIdx.x, q = ln >> 4, c = ln & 15;
    const int n  = nt * 16 + c;
    u16* dp = d + ((kb * NT + nt) * 64 + ln) * 8;
#pragma unroll
    for (int j = 0; j < 8; ++j) {
        int k = kb * 32 + q * 8 + j;
        dp[j] = f2bf((k < Ksrc) ? s[k * N + n] : 0.f);
    }
}

__global__ void pack_all(const float* __restrict__ ee1, const float* __restrict__ ee2,
                         const float* __restrict__ ew1, const float* __restrict__ ew2,
                         const float* __restrict__ nw1, const float* __restrict__ nw2,
                         const float* __restrict__ dw1, u16* __restrict__ ws) {
    int b = blockIdx.x;
    if (b < 8)        { pack_one(ee1, ws + OFF_EE1, 6, 128, 8, b); return; }
    b -= 8;
    if (b < 32)       { pack_one(ee2, ws + OFF_EE2, 128, 128, 8, b); return; }
    b -= 32;
    if (b < 384)      { int l = b / 96;
                        pack_one(ew1 + l*384*128, ws + OFF_EW1 + l*SZ_EW1, 384, 128, 8, b % 96); return; }
    b -= 384;
    if (b < 128)      { int l = b / 32;
                        pack_one(ew2 + l*128*128, ws + OFF_EW2 + l*SZ_EW2, 128, 128, 8, b % 32); return; }
    b -= 128;
    if (b < 256)      { int l = b / 64;
                        pack_one(nw1 + l*256*128, ws + OFF_NW1 + l*SZ_NW1, 256, 128, 8, b % 64); return; }
    b -= 256;
    if (b < 128)      { int l = b / 32;
                        pack_one(nw2 + l*128*128, ws + OFF_NW2 + l*SZ_NW2, 128, 128, 8, b % 32); return; }
    b -= 128;
    pack_one(dw1, ws + OFF_DW1, 128, 64, 4, b);
}

// Wave-level GEMM: bc = first B-fragment (optionally pre-loaded before the phase
// barrier); register double-buffer for subsequent kb.
template<int NMT, int NKB, int NT, typename FA>
__device__ __forceinline__ void wave_gemm(const u16* __restrict__ Wp, int nt, int ln,
                                          bf16x8 bc, FA fa, f32x4* acc) {
    const u16* wp = Wp + (nt * 64 + ln) * 8;
#pragma unroll
    for (int kb = 0; kb < NKB; ++kb) {
        bf16x8 bn;
        if (kb + 1 < NKB) bn = *(const bf16x8*)(wp + (kb + 1) * NT * 512);
#pragma unroll
        for (int mt = 0; mt < NMT; ++mt) {
            bf16x8 a = fa(mt, kb);
            acc[mt] = __builtin_amdgcn_mfma_f32_16x16x32_bf16(a, bc, acc[mt], 0, 0, 0);
        }
        if (kb + 1 < NKB) bc = bn;
    }
}

#define BACC(A, N, b) do { _Pragma("unroll") for (int _i = 0; _i < (N); ++_i) \
                           (A)[_i] = (f32x4){(b), (b), (b), (b)}; } while (0)

// One block (512 thr = 8 waves) per graph; 2-phase layers with SEQUENTIALLY-SCOPED
// edge/node GEMMs (accE's AGPRs die before accN exists -> total regs/wave <= 128
// -> 2 blocks/CU; round 7's concurrent accs hit 88 VGPR -> 1 block/CU). fp32
// residual masters in registers. MFMA C/D: col=lane&15, row=(lane>>4)*4+reg.
extern "C" __global__ void __launch_bounds__(512, 2)
gnn_mfma(const float* __restrict__ x_nodes, const float* __restrict__ damage_locs,
         const float* __restrict__ enc_n_w, const float* __restrict__ enc_n_b,
         const float* __restrict__ enc_e_b1, const float* __restrict__ enc_e_b2,
         const float* __restrict__ edge_b1, const float* __restrict__ edge_b2,
         const float* __restrict__ node_b1, const float* __restrict__ node_b2,
         const float* __restrict__ dec_b1, const float* __restrict__ dec_w2,
         const float* __restrict__ dec_b2,
         const u16* __restrict__ wpack, float* __restrict__ out)
{
    __shared__ __align__(16) u16 smem[169 * ST + 16 * STNIN];
    __shared__ float s_x[NSENS * 2];
    __shared__ float s_dmg[2];
    __shared__ float s_val[NEDGE];
    __shared__ int s_src[NEDGE], s_dst[NEDGE];

    u16* b_he  = smem;               // 72 x ST   edge features (bf16 mirror)
    u16* b_t   = smem + 72 * ST;     // 72 x ST   MLP hidden (edge) / decoder hidden
    u16* b_hn  = smem + 144 * ST;    // 9 x ST    node features
    u16* b_nt  = smem + 153 * ST;    // 16 x ST   node hidden
    u16* b_nin = smem + 169 * ST;    // 16 x STNIN  [h_n | agg]
    u16* b_ph  = b_he;               // alias: phys dead once EE1 consumed it

    const int g   = blockIdx.x;
    const int tid = threadIdx.x;
    const int wv  = tid >> 6, ln = tid & 63;
    const int q   = ln >> 4,  cl = ln & 15;
    const int col = wv * 16 + cl;          // this wave's output column (128-wide GEMMs)

    // 4-row column store (C-fragment -> bf16 mirror)
    auto st4 = [&](u16* buf, int stride, int c, int Rb, int Rlim,
                   float v0, float v1, float v2, float v3) {
        unsigned d01 = cvt2(v0, v1), d23 = cvt2(v2, v3);
        if (Rb + 0 < Rlim) buf[(Rb + 0) * stride + c] = (u16)d01;
        if (Rb + 1 < Rlim) buf[(Rb + 1) * stride + c] = (u16)(d01 >> 16);
        if (Rb + 2 < Rlim) buf[(Rb + 2) * stride + c] = (u16)d23;
        if (Rb + 3 < Rlim) buf[(Rb + 3) * stride + c] = (u16)(d23 >> 16);
    };
    auto preB = [&](const u16* Wp, int nt) -> bf16x8 {
        return *(const bf16x8*)(Wp + (nt * 64 + ln) * 8);
    };

    // ---- zero phys pad region + b_nin rows 9..15 (never written, must be finite) ----
    {
        uint4 z = {0, 0, 0, 0};
        uint4* zp = (uint4*)b_ph;                       // 72*STPH = 2880 u16 = 360 uint4
        for (int i = tid; i < 360; i += 512) zp[i] = z;
        unsigned* znp = (unsigned*)(b_nin + 9 * STNIN); // 7*264 = 1848 u16 = 924 dw
        for (int i = tid; i < 924; i += 512) znp[i] = 0;
    }
    if (tid < NSENS * 2) s_x[tid] = x_nodes[g * NSENS * 2 + tid];
    if (tid < 2)         s_dmg[tid] = damage_locs[g * 2 + tid];
    if (tid < NEDGE) {
        int p = tid >> 1;
        int i = 0, rem = p, cnt = 8;
        while (rem >= cnt) { rem -= cnt; --cnt; ++i; }
        int j = i + 1 + rem;
        s_src[tid] = (tid & 1) ? j : i;
        s_dst[tid] = (tid & 1) ? i : j;
    }
    __syncthreads();

    // ---- phys features -> b_ph (rows<72, cols 0..5 of 32) ----
    if (tid < NEDGE) {
        const int si = s_src[tid], di = s_dst[tid];
        const float sx = s_x[2*si], sy = s_x[2*si+1];
        const float dx = s_x[2*di], dy = s_x[2*di+1];
        const float gx = s_dmg[0],  gy = s_dmg[1];
        const float vx = sx - dx, vy = sy - dy;
        const float vv = vx*vx + vy*vy;
        const float elen = sqrtf(vv + FEPS);
        const float l2 = fmaxf(vv, FEPS);
        float t = ((gx - sx) * (dx - sx) + (gy - sy) * (dy - sy)) / l2;
        t = fminf(fmaxf(t, 0.f), 1.f);
        const float px = sx + t * (dx - sx), py = sy + t * (dy - sy);
        u16* ph = b_ph + tid * STPH;
        ph[0] = f2bf(vx); ph[1] = f2bf(vy); ph[2] = f2bf(elen);
        ph[3] = f2bf(sqrtf((gx-px)*(gx-px) + (gy-py)*(gy-py) + FEPS));
        ph[4] = f2bf(sqrtf((sx-gx)*(sx-gx) + (sy-gy)*(sy-gy) + FEPS));
        ph[5] = f2bf(sqrtf((dx-gx)*(dx-gx) + (dy-gy)*(dy-gy) + FEPS));
    }

    // ---- node encoder (K=2) -> fp32 master m_hn + bf16 mirror (9-row buffer) ----
    f32x4 m_hn;
    {
        const float w0 = enc_n_w[col], w1 = enc_n_w[HDIM + col], bb = enc_n_b[col];
#pragma unroll
        for (int r = 0; r < 4; ++r) {
            const int R = q * 4 + r;
            m_hn[r] = (R < NSENS) ? fmaf(s_x[2*R], w0, fmaf(s_x[2*R+1], w1, bb)) : 0.f;
        }
        st4(b_hn, ST, col, q * 4, NSENS, m_hn[0], m_hn[1], m_hn[2], m_hn[3]);
    }

    // per-lane row offsets (clamped to row 71 -> garbage lands in discarded C rows)
    int rowS[5], rowD[5], rowT[5], rowP[5];
#pragma unroll
    for (int mt = 0; mt < 5; ++mt) {
        int e = mt * 16 + cl; if (e >= NEDGE) e = NEDGE - 1;
        rowS[mt] = s_src[e] * ST; rowD[mt] = s_dst[e] * ST;
        rowT[mt] = e * ST;        rowP[mt] = e * STPH;
    }

    auto fa_t   = [&](int mt, int kb) -> bf16x8 {
        return *(const bf16x8*)(b_t + rowT[mt] + kb * 32 + q * 8); };
    auto fa_ph  = [&](int mt, int kb) -> bf16x8 {
        return *(const bf16x8*)(b_ph + rowP[mt] + q * 8); };
    auto fa_nin = [&](int mt, int kb) -> bf16x8 {
        return *(const bf16x8*)(b_nin + cl * STNIN + kb * 32 + q * 8); };
    auto fa_nt  = [&](int mt, int kb) -> bf16x8 {
        return *(const bf16x8*)(b_nt + cl * ST + kb * 32 + q * 8); };
    auto fa_ein = [&](int mt, int kb) -> bf16x8 {
        const u16* p;
        if (kb < 4)      p = b_hn + rowS[mt] + kb * 32;
        else if (kb < 8) p = b_hn + rowD[mt] + (kb - 4) * 32;
        else             p = b_he + rowT[mt] + (kb - 8) * 32;
        return *(const bf16x8*)(p + q * 8); };

    // write [h_n | (sum-h)/8] for the next layer's node MLP1
    auto write_nin = [&]() {
        float p4 = m_hn[0] + m_hn[1] + m_hn[2] + m_hn[3]; // pad rows are 0 in regs
        p4 += __shfl_xor(p4, 16);
        p4 += __shfl_xor(p4, 32);
        st4(b_nin, STNIN, col, q * 4, NSENS, m_hn[0], m_hn[1], m_hn[2], m_hn[3]);
        st4(b_nin, STNIN, HDIM + col, q * 4, NSENS,
            (p4 - m_hn[0]) * 0.125f, (p4 - m_hn[1]) * 0.125f,
            (p4 - m_hn[2]) * 0.125f, (p4 - m_hn[3]) * 0.125f);
    };

    f32x4 m_he[5];
    bf16x8 pE = preB(wpack + OFF_EE1, wv);   // prefetch EE1's first B before barrier
    __syncthreads();

    // ---- edge encoder GEMM1: relu(phys @ W1 + b1) -> b_t ----
    {
        f32x4 acc[5]; BACC(acc, 5, enc_e_b1[col]);
        wave_gemm<5, 1, 8>(wpack + OFF_EE1, wv, ln, pE, fa_ph, acc);
#pragma unroll
        for (int mt = 0; mt < 5; ++mt)
            st4(b_t, ST, col, mt * 16 + q * 4, NEDGE,
                fmaxf(acc[mt][0], 0.f), fmaxf(acc[mt][1], 0.f),
                fmaxf(acc[mt][2], 0.f), fmaxf(acc[mt][3], 0.f));
        pE = preB(wpack + OFF_EE2, wv);
    }
    __syncthreads();
    // ---- edge encoder GEMM2 -> m_he init + b_he mirror; initial b_nin ----
    {
        f32x4 acc[5]; BACC(acc, 5, enc_e_b2[col]);
        wave_gemm<5, 4, 8>(wpack + OFF_EE2, wv, ln, pE, fa_t, acc);
#pragma unroll
        for (int mt = 0; mt < 5; ++mt) {
            m_he[mt] = acc[mt];
            st4(b_he, ST, col, mt * 16 + q * 4, NEDGE,
                m_he[mt][0], m_he[mt][1], m_he[mt][2], m_he[mt][3]);
        }
        write_nin();
        pE = preB(wpack + OFF_EW1, wv);
    }
    __syncthreads();

    // ---- message-passing layers: 2 barrier-phases each, GEMMs scoped serially ----
    for (int l = 0; l < NLAYER; ++l) {
        // phase A: edge MLP1 then node MLP1 (both read last phase's mirrors)
        {
            {   // EW1: relu([h_src|h_dst|h_e] @ W1 + b1) -> b_t
                f32x4 accE[5]; BACC(accE, 5, edge_b1[l * HDIM + col]);
                wave_gemm<5, 12, 8>(wpack + OFF_EW1 + l * SZ_EW1, wv, ln, pE, fa_ein, accE);
#pragma unroll
                for (int mt = 0; mt < 5; ++mt)
                    st4(b_t, ST, col, mt * 16 + q * 4, NEDGE,
                        fmaxf(accE[mt][0], 0.f), fmaxf(accE[mt][1], 0.f),
                        fmaxf(accE[mt][2], 0.f), fmaxf(accE[mt][3], 0.f));
            }
            {   // NW1: relu([h_n|agg] @ W1 + b1) -> b_nt   (accE's regs recycled)
                f32x4 accN[1]; BACC(accN, 1, node_b1[l * HDIM + col]);
                wave_gemm<1, 8, 8>(wpack + OFF_NW1 + l * SZ_NW1, wv, ln,
                                   preB(wpack + OFF_NW1 + l * SZ_NW1, wv), fa_nin, accN);
                st4(b_nt, ST, col, q * 4, 16,
                    fmaxf(accN[0][0], 0.f), fmaxf(accN[0][1], 0.f),
                    fmaxf(accN[0][2], 0.f), fmaxf(accN[0][3], 0.f));
            }
            pE = preB(wpack + OFF_EW2 + l * SZ_EW2, wv);
        }
        __syncthreads();
        // phase B: edge MLP2 then node MLP2 -> masters += ; refresh mirrors + b_nin
        {
            {   // EW2
                f32x4 accE[5]; BACC(accE, 5, edge_b2[l * HDIM + col]);
                wave_gemm<5, 4, 8>(wpack + OFF_EW2 + l * SZ_EW2, wv, ln, pE, fa_t, accE);
#pragma unroll
                for (int mt = 0; mt < 5; ++mt) {
#pragma unroll
                    for (int r = 0; r < 4; ++r) m_he[mt][r] += accE[mt][r];
                    st4(b_he, ST, col, mt * 16 + q * 4, NEDGE,
                        m_he[mt][0], m_he[mt][1], m_he[mt][2], m_he[mt][3]);
                }
            }
            {   // NW2
                f32x4 accN[1]; BACC(accN, 1, node_b2[l * HDIM + col]);
                wave_gemm<1, 4, 8>(wpack + OFF_NW2 + l * SZ_NW2, wv, ln,
                                   preB(wpack + OFF_NW2 + l * SZ_NW2, wv), fa_nt, accN);
#pragma unroll
                for (int r = 0; r < 4; ++r)
                    if (q * 4 + r < NSENS) m_hn[r] += accN[0][r];
                st4(b_hn, ST, col, q * 4, NSENS, m_hn[0], m_hn[1], m_hn[2], m_hn[3]);
                write_nin();
            }
            if (l + 1 < NLAYER) pE = preB(wpack + OFF_EW1 + (l + 1) * SZ_EW1, wv);
            else                pE = preB(wpack + OFF_DW1, wv & 3);
        }
        __syncthreads();
    }

    // ---- decoder GEMM1 (N=64): relu(h_e @ dec_w1 + b1) -> b_t cols 0..63 ----
    {
        const int ntd = wv & 3;
        const int mt0 = (wv < 4) ? 0 : 2;     // waves 0-3: mt 0-2; waves 4-7: mt 2-4
        int rowDd[3];
#pragma unroll
        for (int mt = 0; mt < 3; ++mt) {
            int e = (mt0 + mt) * 16 + cl; if (e >= NEDGE) e = NEDGE - 1;
            rowDd[mt] = e * ST;
        }
        auto fa_d = [&](int mt, int kb) -> bf16x8 {
            return *(const bf16x8*)(b_he + rowDd[mt] + kb * 32 + q * 8); };
        const int c64 = ntd * 16 + cl;
        f32x4 acc[3]; BACC(acc, 3, dec_b1[c64]);  // (mt=2 twice -> same-value race, benign)
        wave_gemm<3, 4, 4>(wpack + OFF_DW1, ntd, ln, pE, fa_d, acc);
#pragma unroll
        for (int mt = 0; mt < 3; ++mt)
            st4(b_t, ST, c64, (mt0 + mt) * 16 + q * 4, NEDGE,
                fmaxf(acc[mt][0], 0.f), fmaxf(acc[mt][1], 0.f),
                fmaxf(acc[mt][2], 0.f), fmaxf(acc[mt][3], 0.f));
    }
    __syncthreads();
    // ---- decoder GEMM2 (N=1) + sigmoid ----
    if (tid < NEDGE) {
        float a = dec_b2[0];
        const u16* tt = b_t + tid * ST;
#pragma unroll
        for (int k = 0; k < 64; ++k) a = fmaf(bf2f(tt[k]), dec_w2[k], a);
        s_val[tid] = 1.f / (1.f + expf(-a));
    }
    __syncthreads();
    if (tid < NPAIR)
        out[g * NPAIR + tid] = 0.5f * (s_val[2 * tid] + s_val[2 * tid + 1]);
}

extern "C" void kernel_launch(void* const* d_in, const int* in_sizes, int n_in,
                              void* d_out, int out_size, void* d_ws, size_t ws_size,
                              hipStream_t stream) {
    const float* x_nodes     = (const float*)d_in[0];
    const float* damage_locs = (const float*)d_in[1];
    const float* enc_n_w  = (const float*)d_in[2];
    const float* enc_n_b  = (const float*)d_in[3];
    const float* enc_e_w1 = (const float*)d_in[4];
    const float* enc_e_b1 = (const float*)d_in[5];
    const float* enc_e_w2 = (const float*)d_in[6];
    const float* enc_e_b2 = (const float*)d_in[7];
    const float* edge_w1  = (const float*)d_in[8];
    const float* edge_b1  = (const float*)d_in[9];
    const float* edge_w2  = (const float*)d_in[10];
    const float* edge_b2  = (const float*)d_in[11];
    const float* node_w1  = (const float*)d_in[12];
    const float* node_b1  = (const float*)d_in[13];
    const float* node_w2  = (const float*)d_in[14];
    const float* node_b2  = (const float*)d_in[15];
    const float* dec_w1   = (const float*)d_in[16];
    const float* dec_b1   = (const float*)d_in[17];
    const float* dec_w2   = (const float*)d_in[18];
    const float* dec_b2   = (const float*)d_in[19];
    float* out = (float*)d_out;
    u16* ws = (u16*)d_ws;

    hipLaunchKernelGGL(pack_all, dim3(952), dim3(64), 0, stream,
                       enc_e_w1, enc_e_w2, edge_w1, edge_w2, node_w1, node_w2, dec_w1, ws);

    const int ngraph = in_sizes[1] / 2;   // damage_locs is [B,2]
    hipLaunchKernelGGL(gnn_mfma, dim3(ngraph), dim3(512), 0, stream,
                       x_nodes, damage_locs, enc_n_w, enc_n_b,
                       enc_e_b1, enc_e_b2, edge_b1, edge_b2,
                       node_b1, node_b2, dec_b1, dec_w2, dec_b2,
                       ws, out);
}